// Round 1
// baseline (114.023 us; speedup 1.0000x reference)
//
#include <hip/hip_runtime.h>
#include <hip/hip_bf16.h>

#define N_ROWS 4096
#define D_DIM  768
#define MARGIN 1.0f
#define EPS_F  1e-12f

typedef __bf16 bf16x8 __attribute__((ext_vector_type(8)));
typedef float  f32x4  __attribute__((ext_vector_type(4)));
typedef unsigned int u32x4 __attribute__((ext_vector_type(4)));

// ---------------------------------------------------------------------------
// Kernel 1: per-row sum of squares (fp32) + bf16 cast of embeddings
// ---------------------------------------------------------------------------
__global__ __launch_bounds__(256) void prep_kernel(const float* __restrict__ emb,
                                                   __hip_bfloat16* __restrict__ ebf,
                                                   float* __restrict__ sq) {
    const int row = blockIdx.x;
    const float* rp = emb + (size_t)row * D_DIM;
    __hip_bfloat16* op = ebf + (size_t)row * D_DIM;
    float s = 0.f;
    for (int c = threadIdx.x; c < D_DIM; c += 256) {
        float x = rp[c];
        s += x * x;
        op[c] = __float2bfloat16(x);
    }
    // wave64 reduce
    for (int off = 32; off; off >>= 1) s += __shfl_down(s, off, 64);
    __shared__ float wsum[4];
    const int lane = threadIdx.x & 63, w = threadIdx.x >> 6;
    if (lane == 0) wsum[w] = s;
    __syncthreads();
    if (threadIdx.x == 0) sq[row] = wsum[0] + wsum[1] + wsum[2] + wsum[3];
}

// ---------------------------------------------------------------------------
// Kernel 2: 128x128 pair-tile MFMA Gram + fused contrastive-loss epilogue
// Only tiles tj >= ti are computed; off-diagonal tiles weighted x2.
// Sum over ALL ordered pairs i != j, final scale 1/(N*(N-1)).
// ---------------------------------------------------------------------------
#define SLD 56   // LDS row stride in bf16 elems: 112 B = 28 banks, 16B-aligned

__global__ __launch_bounds__(256) void pair_kernel(const __hip_bfloat16* __restrict__ ebf_,
                                                   const float* __restrict__ sq,
                                                   const int* __restrict__ labels,
                                                   float* __restrict__ out) {
    constexpr int T = N_ROWS / 128;   // 32 tile-rows
    // linear block -> (ti, tj) with tj >= ti
    int b = blockIdx.x;
    int ti = 0;
    while (b >= T - ti) { b -= T - ti; ++ti; }
    const int tj = ti + b;
    const int i0 = ti * 128, j0 = tj * 128;

    __shared__ unsigned short lA[128 * SLD];
    __shared__ unsigned short lB[128 * SLD];
    __shared__ float red[4];

    const unsigned short* ebf = (const unsigned short*)ebf_;
    const int tid  = threadIdx.x;
    const int lane = tid & 63;
    const int wave = tid >> 6;
    const int wi   = (wave >> 1) * 64;   // wave's i-offset within tile
    const int wj   = (wave & 1) * 64;    // wave's j-offset within tile
    const int qd   = lane >> 4;          // quad 0..3
    const int ln16 = lane & 15;

    f32x4 acc[4][4];
#pragma unroll
    for (int m = 0; m < 4; ++m)
#pragma unroll
        for (int n = 0; n < 4; ++n) acc[m][n] = (f32x4){0.f, 0.f, 0.f, 0.f};

    // staging map: thread handles rows r0 and r0+64, 8 bf16 (16 B) each
    const int r0 = tid >> 2;
    const int c0 = (tid & 3) * 8;

    const size_t baseA0 = (size_t)(i0 + r0) * D_DIM + c0;
    const size_t baseA1 = baseA0 + (size_t)64 * D_DIM;
    const size_t baseB0 = (size_t)(j0 + r0) * D_DIM + c0;
    const size_t baseB1 = baseB0 + (size_t)64 * D_DIM;

    for (int k0 = 0; k0 < D_DIM; k0 += 32) {
        u32x4 a0 = *(const u32x4*)(ebf + baseA0 + k0);
        u32x4 a1 = *(const u32x4*)(ebf + baseA1 + k0);
        u32x4 b0 = *(const u32x4*)(ebf + baseB0 + k0);
        u32x4 b1 = *(const u32x4*)(ebf + baseB1 + k0);

        __syncthreads();   // previous iteration's LDS reads complete
        *(u32x4*)&lA[r0 * SLD + c0]        = a0;
        *(u32x4*)&lA[(r0 + 64) * SLD + c0] = a1;
        *(u32x4*)&lB[r0 * SLD + c0]        = b0;
        *(u32x4*)&lB[(r0 + 64) * SLD + c0] = b1;
        __syncthreads();   // LDS tiles ready

        bf16x8 af[4], bfr[4];
#pragma unroll
        for (int m = 0; m < 4; ++m)
            af[m] = *(const bf16x8*)&lA[(wi + m * 16 + ln16) * SLD + qd * 8];
#pragma unroll
        for (int n = 0; n < 4; ++n)
            bfr[n] = *(const bf16x8*)&lB[(wj + n * 16 + ln16) * SLD + qd * 8];
#pragma unroll
        for (int m = 0; m < 4; ++m)
#pragma unroll
            for (int n = 0; n < 4; ++n)
                acc[m][n] = __builtin_amdgcn_mfma_f32_16x16x32_bf16(
                    af[m], bfr[n], acc[m][n], 0, 0, 0);
    }

    // ---- epilogue: contrastive loss per pair, accumulate ----
    float psum = 0.f;
#pragma unroll
    for (int m = 0; m < 4; ++m) {
#pragma unroll
        for (int n = 0; n < 4; ++n) {
#pragma unroll
            for (int r = 0; r < 4; ++r) {
                const int gi = i0 + wi + m * 16 + qd * 4 + r;  // C row
                const int gj = j0 + wj + n * 16 + ln16;        // C col
                const float g  = acc[m][n][r];
                float d2 = sq[gi] + sq[gj] - 2.0f * g;
                d2 = fmaxf(d2, 0.0f);
                const float dist = sqrtf(d2 + EPS_F);
                const float h = fmaxf(MARGIN - dist, 0.0f);
                const float pl = (labels[gi] == labels[gj]) ? d2 : h * h;
                if (gi != gj) psum += pl;
            }
        }
    }

    for (int off = 32; off; off >>= 1) psum += __shfl_down(psum, off, 64);
    if (lane == 0) red[wave] = psum;
    __syncthreads();
    if (tid == 0) {
        const float wgt = (ti == tj) ? 1.0f : 2.0f;
        const float scale = 1.0f / ((float)N_ROWS * (float)(N_ROWS - 1));
        atomicAdd(out, (red[0] + red[1] + red[2] + red[3]) * wgt * scale);
    }
}

// ---------------------------------------------------------------------------
extern "C" void kernel_launch(void* const* d_in, const int* in_sizes, int n_in,
                              void* d_out, int out_size, void* d_ws, size_t ws_size,
                              hipStream_t stream) {
    const float* emb   = (const float*)d_in[0];
    const int* labels  = (const int*)d_in[1];
    float* out         = (float*)d_out;

    __hip_bfloat16* ebf = (__hip_bfloat16*)d_ws;
    float* sq = (float*)((char*)d_ws + (size_t)N_ROWS * D_DIM * sizeof(__hip_bfloat16));

    hipMemsetAsync(d_out, 0, sizeof(float), stream);
    prep_kernel<<<N_ROWS, 256, 0, stream>>>(emb, ebf, sq);

    constexpr int T = N_ROWS / 128;
    constexpr int nblk = T * (T + 1) / 2;   // 528 tiles, tj >= ti
    pair_kernel<<<nblk, 256, 0, stream>>>(ebf, sq, labels, out);
}

// Round 2
// 106.868 us; speedup vs baseline: 1.0670x; 1.0670x over previous
//
#include <hip/hip_runtime.h>
#include <hip/hip_bf16.h>

#define N_ROWS 4096
#define D_DIM  768
#define MARGIN 1.0f
#define EPS_F  1e-12f

typedef __bf16 bf16x8 __attribute__((ext_vector_type(8)));
typedef float  f32x4  __attribute__((ext_vector_type(4)));
typedef unsigned int u32x4 __attribute__((ext_vector_type(4)));

// ---------------------------------------------------------------------------
// Kernel 1: per-row sum of squares (fp32) + bf16 cast, one wave per row.
// 4096 rows / 4 waves per block -> 1024 blocks. float4 loads, 8B bf16 stores.
// ---------------------------------------------------------------------------
__global__ __launch_bounds__(256) void prep_kernel(const float* __restrict__ emb,
                                                   unsigned short* __restrict__ ebf,
                                                   float* __restrict__ sq) {
    const int wave = threadIdx.x >> 6;
    const int lane = threadIdx.x & 63;
    const int row  = blockIdx.x * 4 + wave;

    const float4* rp = (const float4*)(emb + (size_t)row * D_DIM);   // 192 float4/row
    unsigned short* op = ebf + (size_t)row * D_DIM;

    float s = 0.f;
#pragma unroll
    for (int t = 0; t < 3; ++t) {
        const int idx = lane + t * 64;
        float4 v = rp[idx];
        s += v.x * v.x + v.y * v.y + v.z * v.z + v.w * v.w;
        union { ushort4 u4; __hip_bfloat16 h[4]; } o;
        o.h[0] = __float2bfloat16(v.x);
        o.h[1] = __float2bfloat16(v.y);
        o.h[2] = __float2bfloat16(v.z);
        o.h[3] = __float2bfloat16(v.w);
        *(ushort4*)(op + idx * 4) = o.u4;
    }
    for (int off = 32; off; off >>= 1) s += __shfl_down(s, off, 64);
    if (lane == 0) sq[row] = s;
}

// ---------------------------------------------------------------------------
// Kernel 2: 64x64 pair-tile MFMA Gram + fused contrastive-loss epilogue.
// 2080 blocks (tj >= ti), 256 threads = 4 waves, each wave a 32x32 quadrant.
// BK=64 (12 K-iters). Off-diagonal tiles weighted x2; diagonal skips i==j.
// Final scale 1/(N*(N-1)).
// ---------------------------------------------------------------------------
#define SLD 72   // LDS row stride (bf16 elems): 144 B -> conflict-free r/w maps

__global__ __launch_bounds__(256, 4) void pair_kernel(const __hip_bfloat16* __restrict__ ebf_,
                                                      const float* __restrict__ sq,
                                                      const int* __restrict__ labels,
                                                      float* __restrict__ out) {
    constexpr int T = N_ROWS / 64;   // 64 tile-rows
    int b = blockIdx.x;
    int ti = 0;
    while (b >= T - ti) { b -= T - ti; ++ti; }
    const int tj = ti + b;
    const int i0 = ti * 64, j0 = tj * 64;

    __shared__ __align__(16) unsigned short lA[64 * SLD];
    __shared__ __align__(16) unsigned short lB[64 * SLD];
    __shared__ float red[4];

    const unsigned short* ebf = (const unsigned short*)ebf_;
    const int tid  = threadIdx.x;
    const int lane = tid & 63;
    const int wave = tid >> 6;
    const int wi   = (wave >> 1) * 32;   // wave i-offset in tile
    const int wj   = (wave & 1) * 32;    // wave j-offset in tile
    const int qd   = lane >> 4;
    const int ln16 = lane & 15;

    f32x4 acc[2][2];
#pragma unroll
    for (int m = 0; m < 2; ++m)
#pragma unroll
        for (int n = 0; n < 2; ++n) acc[m][n] = (f32x4){0.f, 0.f, 0.f, 0.f};

    // staging map: thread -> rows sr and sr+32, 8 bf16 (16 B) at col chunk sc
    const int sr = tid >> 3;          // 0..31
    const int sc = (tid & 7) * 8;     // 0..56
    const size_t gA0 = (size_t)(i0 + sr) * D_DIM + sc;
    const size_t gA1 = gA0 + (size_t)32 * D_DIM;
    const size_t gB0 = (size_t)(j0 + sr) * D_DIM + sc;
    const size_t gB1 = gB0 + (size_t)32 * D_DIM;

    for (int k0 = 0; k0 < D_DIM; k0 += 64) {
        u32x4 a0 = *(const u32x4*)(ebf + gA0 + k0);
        u32x4 a1 = *(const u32x4*)(ebf + gA1 + k0);
        u32x4 b0 = *(const u32x4*)(ebf + gB0 + k0);
        u32x4 b1 = *(const u32x4*)(ebf + gB1 + k0);

        __syncthreads();   // previous iteration's LDS reads done
        *(u32x4*)&lA[sr * SLD + sc]        = a0;
        *(u32x4*)&lA[(sr + 32) * SLD + sc] = a1;
        *(u32x4*)&lB[sr * SLD + sc]        = b0;
        *(u32x4*)&lB[(sr + 32) * SLD + sc] = b1;
        __syncthreads();   // tiles ready

#pragma unroll
        for (int kt = 0; kt < 2; ++kt) {
            bf16x8 af[2], bv[2];
            af[0] = *(const bf16x8*)&lA[(wi + ln16) * SLD      + kt * 32 + qd * 8];
            af[1] = *(const bf16x8*)&lA[(wi + 16 + ln16) * SLD + kt * 32 + qd * 8];
            bv[0] = *(const bf16x8*)&lB[(wj + ln16) * SLD      + kt * 32 + qd * 8];
            bv[1] = *(const bf16x8*)&lB[(wj + 16 + ln16) * SLD + kt * 32 + qd * 8];
#pragma unroll
            for (int m = 0; m < 2; ++m)
#pragma unroll
                for (int n = 0; n < 2; ++n)
                    acc[m][n] = __builtin_amdgcn_mfma_f32_16x16x32_bf16(
                        af[m], bv[n], acc[m][n], 0, 0, 0);
        }
    }

    // ---- epilogue: contrastive loss per pair ----
    float psum = 0.f;
#pragma unroll
    for (int m = 0; m < 2; ++m) {
#pragma unroll
        for (int n = 0; n < 2; ++n) {
#pragma unroll
            for (int r = 0; r < 4; ++r) {
                const int gi = i0 + wi + m * 16 + qd * 4 + r;  // C row
                const int gj = j0 + wj + n * 16 + ln16;        // C col
                const float g = acc[m][n][r];
                float d2 = fmaxf(sq[gi] + sq[gj] - 2.0f * g, 0.0f);
                const float dist = sqrtf(d2 + EPS_F);
                const float h = fmaxf(MARGIN - dist, 0.0f);
                const float pl = (labels[gi] == labels[gj]) ? d2 : h * h;
                if (gi != gj) psum += pl;
            }
        }
    }

    for (int off = 32; off; off >>= 1) psum += __shfl_down(psum, off, 64);
    if (lane == 0) red[wave] = psum;
    __syncthreads();
    if (tid == 0) {
        const float wgt = (ti == tj) ? 1.0f : 2.0f;
        const float scale = 1.0f / ((float)N_ROWS * (float)(N_ROWS - 1));
        atomicAdd(out, (red[0] + red[1] + red[2] + red[3]) * wgt * scale);
    }
}

// ---------------------------------------------------------------------------
extern "C" void kernel_launch(void* const* d_in, const int* in_sizes, int n_in,
                              void* d_out, int out_size, void* d_ws, size_t ws_size,
                              hipStream_t stream) {
    const float* emb  = (const float*)d_in[0];
    const int* labels = (const int*)d_in[1];
    float* out        = (float*)d_out;

    unsigned short* ebf = (unsigned short*)d_ws;
    float* sq = (float*)((char*)d_ws + (size_t)N_ROWS * D_DIM * sizeof(unsigned short));

    hipMemsetAsync(d_out, 0, sizeof(float), stream);
    prep_kernel<<<N_ROWS / 4, 256, 0, stream>>>(emb, ebf, sq);

    constexpr int T = N_ROWS / 64;
    constexpr int nblk = T * (T + 1) / 2;   // 2080 tiles, tj >= ti
    pair_kernel<<<nblk, 256, 0, stream>>>((const __hip_bfloat16*)ebf, sq, labels, out);
}

// Round 3
// 104.385 us; speedup vs baseline: 1.0923x; 1.0238x over previous
//
#include <hip/hip_runtime.h>
#include <hip/hip_bf16.h>

#define N_ROWS 4096
#define D_DIM  768
#define MARGIN 1.0f
#define EPS_F  1e-12f
#define BK 64            // K-chunk per LDS stage (64 bf16 = 128 B per row)

typedef __bf16 bf16x8 __attribute__((ext_vector_type(8)));
typedef float  f32x4  __attribute__((ext_vector_type(4)));

// async global->LDS DMA, 16 B per lane; LDS dst = wave-uniform base + lane*16
#define GLD16(gp, lp)                                                          \
    __builtin_amdgcn_global_load_lds(                                         \
        (const __attribute__((address_space(1))) void*)(gp),                  \
        (__attribute__((address_space(3))) void*)(lp), 16, 0, 0)

// ---------------------------------------------------------------------------
// Kernel 1: per-row sum of squares (fp32) + bf16 cast, one wave per row.
// ---------------------------------------------------------------------------
__global__ __launch_bounds__(256) void prep_kernel(const float* __restrict__ emb,
                                                   unsigned short* __restrict__ ebf,
                                                   float* __restrict__ sq) {
    const int wave = threadIdx.x >> 6;
    const int lane = threadIdx.x & 63;
    const int row  = blockIdx.x * 4 + wave;

    const float4* rp = (const float4*)(emb + (size_t)row * D_DIM);   // 192 float4/row
    unsigned short* op = ebf + (size_t)row * D_DIM;

    float s = 0.f;
#pragma unroll
    for (int t = 0; t < 3; ++t) {
        const int idx = lane + t * 64;
        float4 v = rp[idx];
        s += v.x * v.x + v.y * v.y + v.z * v.z + v.w * v.w;
        union { ushort4 u4; __hip_bfloat16 h[4]; } o;
        o.h[0] = __float2bfloat16(v.x);
        o.h[1] = __float2bfloat16(v.y);
        o.h[2] = __float2bfloat16(v.z);
        o.h[3] = __float2bfloat16(v.w);
        *(ushort4*)(op + idx * 4) = o.u4;
    }
    for (int off = 32; off; off >>= 1) s += __shfl_down(s, off, 64);
    if (lane == 0) sq[row] = s;
}

// ---------------------------------------------------------------------------
// Kernel 2: 128x128 pair-tile, global_load_lds(16B) staging with XOR-swizzled
// LDS layout (unpadded, stride 64 elems = 128 B). 528 blocks (tj >= ti),
// 4 waves, each wave a 64x64 quadrant with 4x4 16x16x32 frags.
// LDS granule s of row r holds global granule s ^ (r&7); reads use
// granule (4kt+qd) ^ (ln16&7)  ->  8 lanes per 4-bank group, conflict-free.
// ---------------------------------------------------------------------------
__global__ __launch_bounds__(256) void pair_kernel(const __hip_bfloat16* __restrict__ ebf_,
                                                   const float* __restrict__ sq,
                                                   const int* __restrict__ labels,
                                                   float* __restrict__ out) {
    constexpr int T = N_ROWS / 128;   // 32 tile-rows, 528 tiles
    int b = blockIdx.x;
    int ti = 0;
    while (b >= T - ti) { b -= T - ti; ++ti; }
    const int tj = ti + b;
    const int i0 = ti * 128, j0 = tj * 128;

    __shared__ __align__(16) unsigned short lA[128 * BK];   // 16 KiB
    __shared__ __align__(16) unsigned short lB[128 * BK];   // 16 KiB
    __shared__ float red[4];

    const unsigned short* ebf = (const unsigned short*)ebf_;
    const int tid  = threadIdx.x;
    const int lane = tid & 63;
    const int wave = tid >> 6;
    const int wi   = (wave >> 1) * 64;
    const int wj   = (wave & 1) * 64;
    const int qd   = lane >> 4;
    const int ln16 = lane & 15;

    f32x4 acc[4][4];
#pragma unroll
    for (int m = 0; m < 4; ++m)
#pragma unroll
        for (int n = 0; n < 4; ++n) acc[m][n] = (f32x4){0.f, 0.f, 0.f, 0.f};

    // staging source map: lane l covers row (+l>>3), LDS granule l&7 which
    // holds global granule (l&7)^(l>>3)
    const int gr = lane >> 3;               // 0..7
    const int gg = (lane & 7) ^ gr;         // swizzled source granule
    // wave stages rows [wave*32, wave*32+32) in 4 chunks of 8 rows
    const unsigned short* gA = ebf + (size_t)(i0 + wave * 32 + gr) * D_DIM + gg * 8;
    const unsigned short* gB = ebf + (size_t)(j0 + wave * 32 + gr) * D_DIM + gg * 8;
    unsigned short* dA = &lA[(wave * 32) * BK];
    unsigned short* dB = &lB[(wave * 32) * BK];

    for (int k0 = 0; k0 < D_DIM; k0 += BK) {
        if (k0) __syncthreads();            // prior reads done before overwrite
#pragma unroll
        for (int inst = 0; inst < 4; ++inst) {
            GLD16(gA + (size_t)inst * 8 * D_DIM + k0, dA + inst * 8 * BK);
            GLD16(gB + (size_t)inst * 8 * D_DIM + k0, dB + inst * 8 * BK);
        }
        __syncthreads();                    // vmcnt(0) drained: tiles ready

#pragma unroll
        for (int kt = 0; kt < 2; ++kt) {
            const int sg = ((kt << 2) + qd) ^ (ln16 & 7);   // swizzled granule
            bf16x8 af[4], bv[4];
#pragma unroll
            for (int m = 0; m < 4; ++m)
                af[m] = *(const bf16x8*)&lA[(wi + m * 16 + ln16) * BK + sg * 8];
#pragma unroll
            for (int n = 0; n < 4; ++n)
                bv[n] = *(const bf16x8*)&lB[(wj + n * 16 + ln16) * BK + sg * 8];
#pragma unroll
            for (int m = 0; m < 4; ++m)
#pragma unroll
                for (int n = 0; n < 4; ++n)
                    acc[m][n] = __builtin_amdgcn_mfma_f32_16x16x32_bf16(
                        af[m], bv[n], acc[m][n], 0, 0, 0);
        }
    }

    // ---- epilogue: contrastive loss per pair ----
    float psum = 0.f;
#pragma unroll
    for (int m = 0; m < 4; ++m) {
#pragma unroll
        for (int n = 0; n < 4; ++n) {
#pragma unroll
            for (int r = 0; r < 4; ++r) {
                const int gi = i0 + wi + m * 16 + qd * 4 + r;  // C row
                const int gj = j0 + wj + n * 16 + ln16;        // C col
                const float g = acc[m][n][r];
                float d2 = fmaxf(sq[gi] + sq[gj] - 2.0f * g, 0.0f);
                const float dist = sqrtf(d2 + EPS_F);
                const float h = fmaxf(MARGIN - dist, 0.0f);
                const float pl = (labels[gi] == labels[gj]) ? d2 : h * h;
                if (gi != gj) psum += pl;
            }
        }
    }

    for (int off = 32; off; off >>= 1) psum += __shfl_down(psum, off, 64);
    if (lane == 0) red[wave] = psum;
    __syncthreads();
    if (tid == 0) {
        const float wgt = (ti == tj) ? 1.0f : 2.0f;
        const float scale = 1.0f / ((float)N_ROWS * (float)(N_ROWS - 1));
        atomicAdd(out, (red[0] + red[1] + red[2] + red[3]) * wgt * scale);
    }
}

// ---------------------------------------------------------------------------
extern "C" void kernel_launch(void* const* d_in, const int* in_sizes, int n_in,
                              void* d_out, int out_size, void* d_ws, size_t ws_size,
                              hipStream_t stream) {
    const float* emb  = (const float*)d_in[0];
    const int* labels = (const int*)d_in[1];
    float* out        = (float*)d_out;

    unsigned short* ebf = (unsigned short*)d_ws;
    float* sq = (float*)((char*)d_ws + (size_t)N_ROWS * D_DIM * sizeof(unsigned short));

    hipMemsetAsync(d_out, 0, sizeof(float), stream);
    prep_kernel<<<N_ROWS / 4, 256, 0, stream>>>(emb, ebf, sq);

    constexpr int T = N_ROWS / 128;
    constexpr int nblk = T * (T + 1) / 2;   // 528 tiles, tj >= ti
    pair_kernel<<<nblk, 256, 0, stream>>>((const __hip_bfloat16*)ebf, sq, labels, out);
}